// Round 8
// baseline (224.354 us; speedup 1.0000x reference)
//
#include <hip/hip_runtime.h>

// Problem constants (B=4, H=W=64, C=256, GROUPS=8)
#define N_TOK 4096          // H*W
#define C_DIM 256
#define BATCH 4
#define M_ROWS (BATCH * N_TOK)   // 16384
#define GN_CNT 131072.0f         // 64*64*32 elements per (b, group)

typedef __attribute__((ext_vector_type(4))) float f32x4;
typedef __attribute__((ext_vector_type(16))) float f32x16;
typedef __attribute__((ext_vector_type(8))) short s16x8;      // 8 x bf16 (MFMA A/B frag)
typedef __attribute__((ext_vector_type(4))) unsigned short u16x4;
typedef __attribute__((ext_vector_type(4))) unsigned int u32x4;

static __device__ __forceinline__ unsigned short f2bf(float f) {
  unsigned int u = __builtin_bit_cast(unsigned int, f);
  u += 0x7fff + ((u >> 16) & 1);   // RNE
  return (unsigned short)(u >> 16);
}
static __device__ __forceinline__ float bf2f(unsigned short h) {
  unsigned int u = ((unsigned int)h) << 16;
  return __builtin_bit_cast(float, u);
}

// async global->LDS DMA, 16 B per lane; LDS dest = wave-uniform base + lane*16.
static __device__ __forceinline__ void gload_lds16(const void* g, void* l) {
  __builtin_amdgcn_global_load_lds(
      (__attribute__((address_space(1))) void*)(unsigned long long)(const char*)g,
      (__attribute__((address_space(3))) void*)l, 16, 0, 0);
}

// ---- prep: gn partial stats (blocks 0..511, no atomics) + wtrans (512..767) --
__global__ __launch_bounds__(256) void prep(const float* __restrict__ x,
                                            const float* __restrict__ wq,
                                            const float* __restrict__ wk,
                                            const float* __restrict__ wv,
                                            const float* __restrict__ wp,
                                            float* __restrict__ partials,
                                            unsigned short* __restrict__ wT) {
  int tid = threadIdx.x;
  if (blockIdx.x < 512) {
    // ---- GroupNorm partial stats: slot = (bg*16+chunk), overwrite (no init) --
    int bg = blockIdx.x >> 4, chunk = blockIdx.x & 15;
    int b = bg >> 3, g = bg & 7;
    const f32x4* x4 = (const f32x4*)x;
    float s1 = 0.f, s2 = 0.f;
#pragma unroll
    for (int it = 0; it < 8; ++it) {
      int idx = it * 256 + tid;
      int nl = idx >> 3, cq = idx & 7;
      f32x4 v = x4[(b * N_TOK + chunk * 256 + nl) * 64 + g * 8 + cq];
      s1 += v[0] + v[1] + v[2] + v[3];
      s2 += v[0] * v[0] + v[1] * v[1] + v[2] * v[2] + v[3] * v[3];
    }
    for (int m = 1; m < 64; m <<= 1) {
      s1 += __shfl_xor(s1, m, 64);
      s2 += __shfl_xor(s2, m, 64);
    }
    __shared__ float r1[4], r2[4];
    int wave = tid >> 6, lane = tid & 63;
    if (lane == 0) { r1[wave] = s1; r2[wave] = s2; }
    __syncthreads();
    if (tid == 0) {
      int slot = (bg * 16 + chunk) * 2;
      partials[slot]     = r1[0] + r1[1] + r1[2] + r1[3];
      partials[slot + 1] = r2[0] + r2[1] + r2[2] + r2[3];
    }
  } else {
    // ---- weight fp32 -> bf16 transposed: wT[n][k] = w[k][n] ----
    int rem = blockIdx.x - 512;
    int z = rem >> 6, t = rem & 63;
    int k0 = (t >> 3) * 32, n0 = (t & 7) * 32;
    const float* const srcs[4] = {wq, wk, wv, wp};
    const float* w = srcs[z];
    unsigned short* o = wT + z * 65536;
    __shared__ float tt[32][33];
    int tx = tid & 31, ty = tid >> 5;
#pragma unroll
    for (int ky = 0; ky < 32; ky += 8)
      tt[ty + ky][tx] = w[(k0 + ty + ky) * C_DIM + n0 + tx];
    __syncthreads();
#pragma unroll
    for (int ky = 0; ky < 32; ky += 8)
      o[(n0 + ty + ky) * C_DIM + k0 + tx] = f2bf(tt[tx][ty + ky]);
  }
}

// ---- W tile staging: 16 iters = 64 KB (128 n x 256 k bf16), src-swizzled ----
// NOTE: a full W tile is 32768 shorts = 64 KB. R7's Wt[2][16384] (32 KB/buf)
// overflowed -> corruption. Double-buffering needs 128 KB/block -> impossible
// at 2 blocks/CU (160 KB LDS). Single-buffer is the structural choice.
static __device__ __forceinline__ void stage_W(unsigned short* dst,
                                               const unsigned short* src,
                                               int c0, int tid) {
#pragma unroll
  for (int ii = 0; ii < 16; ++ii) {
    int u = ii * 256 + tid;
    int n = u >> 5, ku = u & 31;
    gload_lds16(src + (size_t)(c0 + n) * C_DIM + ((ku ^ (n & 7)) * 8), dst + u * 8);
  }
}

// ------ QKV GEMM, GroupNorm fused, V-transpose fused --------------------------
// v8: R6-proven single-buffer W structure; GN stats per-wave via __shfl
// broadcast (no LDS/barrier dependency; af-build overlaps the W(q) DMA).
__global__ __launch_bounds__(256, 2) void qkv_gemm(const float* __restrict__ x,
                                                   const unsigned short* __restrict__ wT,
                                                   const float* __restrict__ partials,
                                                   const float* __restrict__ gamma,
                                                   const float* __restrict__ beta,
                                                   const float* __restrict__ bq,
                                                   const float* __restrict__ bk,
                                                   const float* __restrict__ bv,
                                                   unsigned short* __restrict__ qo,
                                                   unsigned short* __restrict__ ko,
                                                   unsigned short* __restrict__ vTo) {
  int tid = threadIdx.x;
  int wave = tid >> 6, lane = tid & 63, n32 = lane & 31, half = lane >> 5;
  int rg = wave >> 1, cv = wave & 1;
  int row0 = blockIdx.x * 64 + rg * 32;
  int c0 = blockIdx.y * 128;
  int row = row0 + n32;
  int batch = blockIdx.x >> 6;               // 64 rowblocks per batch
  __shared__ __align__(16) unsigned short Wt[32768];   // 64 KB: one full W tile

  stage_W(Wt, wT, c0, tid);                  // W(q) in flight

  // per-wave GN stats, no barrier: lane computes group (lane&7), shfl broadcast
  float mean[8], rstd[8];
  {
    const float* p = partials + (batch * 8 + (lane & 7)) * 32;   // 16 chunks x 2
    float s1 = 0.f, s2 = 0.f;
#pragma unroll
    for (int c = 0; c < 16; ++c) { s1 += p[2 * c]; s2 += p[2 * c + 1]; }
    float inv = 1.f / GN_CNT;
    float m = s1 * inv, v = s2 * inv - m * m;
    float rs = rsqrtf(v + 1e-3f);
#pragma unroll
    for (int g = 0; g < 8; ++g) { mean[g] = __shfl(m, g); rstd[g] = __shfl(rs, g); }
  }

  // A-fragments: GroupNorm(x) inline, bf16-packed; k-unit = 2ks+half
  s16x8 af[16];
#pragma unroll
  for (int ks = 0; ks < 16; ++ks) {
    int cb = ks * 16 + half * 8;
    const f32x4* xp = (const f32x4*)(x + (size_t)row * C_DIM + cb);
    f32x4 v0 = xp[0], v1 = xp[1];
    const f32x4* g4 = (const f32x4*)(gamma + cb);
    const f32x4* b4 = (const f32x4*)(beta + cb);
    f32x4 ga0 = g4[0], ga1 = g4[1], be0 = b4[0], be1 = b4[1];
    int g = (2 * ks + half) >> 2;
    float m = mean[g], rs = rstd[g];
    s16x8 o;
#pragma unroll
    for (int j = 0; j < 4; ++j) {
      o[j]     = (short)f2bf((v0[j] - m) * rs * ga0[j] + be0[j]);
      o[4 + j] = (short)f2bf((v1[j] - m) * rs * ga1[j] + be1[j]);
    }
    af[ks] = o;
  }
  __syncthreads();   // W(q) resident

  f32x16 vacc[2];
  for (int w = 0; w < 3; ++w) {
    if (w > 0) {
      __syncthreads();   // previous W reads done
      stage_W(Wt, wT + (size_t)w * 65536, c0, tid);
      __syncthreads();   // new W resident
    }
    const float* bias = (w == 0) ? bq : (w == 1) ? bk : bv;
    unsigned short* outp = (w == 0) ? qo : ko;
    float scale = (w == 0) ? 0.0625f : 1.f;  // q absorbs softmax scale C^-0.5
#pragma unroll
    for (int ct = 0; ct < 2; ++ct) {
      int nl = (cv * 2 + ct) * 32 + n32;
      f32x16 acc = (f32x16)(bias[c0 + nl]);
#pragma unroll
      for (int ks = 0; ks < 16; ++ks) {
        s16x8 wf = *(const s16x8*)(Wt + nl * C_DIM + (((2 * ks + half) ^ (nl & 7)) * 8));
        acc = __builtin_amdgcn_mfma_f32_32x32x16_bf16(af[ks], wf, acc, 0, 0, 0);
      }
      if (w < 2) {
#pragma unroll
        for (int r = 0; r < 16; ++r) {
          int rr = (r & 3) + 8 * (r >> 2) + 4 * half;
          outp[(size_t)(row0 + rr) * C_DIM + c0 + nl] = f2bf(acc[r] * scale);
        }
      } else {
        vacc[ct] = acc;
      }
    }
  }

  // ---- fused V transpose: vacc -> Wt as [128 ch][72] -> coalesced vT stores --
  __syncthreads();                 // all Wt reads for w==2 complete
#pragma unroll
  for (int ct = 0; ct < 2; ++ct) {
    int ch = (cv * 2 + ct) * 32 + n32;
#pragma unroll
    for (int g = 0; g < 4; ++g) {
      u16x4 pk;
#pragma unroll
      for (int j = 0; j < 4; ++j) pk[j] = f2bf(vacc[ct][g * 4 + j]);
      int tok = rg * 32 + 8 * g + 4 * half;   // tokens within block (0..63)
      *(u16x4*)&Wt[ch * 72 + tok] = pk;
    }
  }
  __syncthreads();
  {
    int ch = tid >> 1, nh = tid & 1;          // 128 ch x 2 token-halves
    int tokb = (blockIdx.x & 63) * 64;        // token base within batch
    const u32x4* srcp = (const u32x4*)&Wt[ch * 72 + nh * 32];
    u32x4* dstp = (u32x4*)&vTo[((size_t)(batch * C_DIM + c0 + ch)) * N_TOK + tokb + nh * 32];
#pragma unroll
    for (int qq = 0; qq < 4; ++qq) dstp[qq] = srcp[qq];
  }
}

// ---- K staging: ks-major, lane-linear within ks block ------------------------
// QK read for lane (n32,half) at ks is byte ks*1024 + lane*16: each 16-lane
// quarter reads 256 B CONTIGUOUS -> zero bank conflicts (verified R5: 4.19M->0).
static __device__ __forceinline__ void stage_K(unsigned short* dst,
                                               const unsigned short* kb,
                                               int jbase, int tid) {
#pragma unroll
  for (int ii = 0; ii < 4; ++ii) {
    int u = ii * 256 + tid;
    int ksu = u >> 6, hf = (u >> 5) & 1, tok = u & 31;
    gload_lds16(kb + (size_t)(jbase + tok) * C_DIM + ksu * 16 + hf * 8, dst + u * 8);
  }
}
static __device__ __forceinline__ void stage_V(unsigned short* dst,
                                               const unsigned short* vb,
                                               int jbase, int tid) {
#pragma unroll
  for (int ii = 0; ii < 4; ++ii)
    gload_lds16(vb + (size_t)tid * N_TOK + jbase + ii * 8, dst + (ii * 256 + tid) * 8);
}

// ------- Flash attention partial, v8: QK(jt) interleaved with PV(jt-1) --------
// Phase A interleaves QK's 16 serially-dependent MFMAs with PV(jt-1)'s 16
// independent MFMAs (chain stalls filled); phase B is softmax(jt) standalone.
// Dataflow identical to the R6-passing fused loop (pf consumed in A, rebuilt
// in B; same V rotation). V triple-buffer, K double. One syncthreads/jt.
__global__ __launch_bounds__(256, 2) void attn_part(const unsigned short* __restrict__ q,
                                                    const unsigned short* __restrict__ k,
                                                    const unsigned short* __restrict__ vT,
                                                    unsigned short* __restrict__ op0,
                                                    unsigned short* __restrict__ op1,
                                                    unsigned short* __restrict__ op2,
                                                    unsigned short* __restrict__ op3,
                                                    float* __restrict__ lbuf) {
  int tid = threadIdx.x;
  int wave = tid >> 6, lane = tid & 63;
  int n32 = lane & 31, half = lane >> 5;
  int i = blockIdx.x;
  int batch = (i >> 1) & 3;
  int slot = ((i >> 3) << 1) | (i & 1);      // 0..127
  int qb = slot & 31, chunk = slot >> 5;     // 32 row-blocks x 4 chunks
  int qrow0 = batch * N_TOK + qb * 128 + wave * 32;
  const unsigned short* kb = k + (size_t)batch * N_TOK * C_DIM;
  const unsigned short* vb = vT + (size_t)batch * C_DIM * N_TOK;
  unsigned short* op = (chunk == 0) ? op0 : (chunk == 1) ? op1 : (chunk == 2) ? op2 : op3;

  __shared__ __align__(16) unsigned short K_lds[2][8192];  // ks-major, lane-linear
  __shared__ __align__(16) unsigned short V_lds[3][8192];  // jb-major: jb*256 + ch

  int jbase0 = chunk * 1024;
  stage_K(K_lds[0], kb, jbase0, tid);
  stage_V(V_lds[0], vb, jbase0, tid);

  const unsigned short* qp = q + (size_t)(qrow0 + n32) * C_DIM;
  s16x8 qf[16];
#pragma unroll
  for (int ks = 0; ks < 16; ++ks)
    qf[ks] = *(const s16x8*)(qp + ks * 16 + half * 8);

  f32x16 Oa[8];
#pragma unroll
  for (int ct = 0; ct < 8; ++ct) Oa[ct] = (f32x16)(0.f);
  float ls = 0.f;

  __syncthreads();   // tile 0 resident (drains qf loads too)

  // start tile 1 DMA, then compute QK(0) + softmax(0) -> pf persist regs
  stage_K(K_lds[1], kb, jbase0 + 32, tid);
  stage_V(V_lds[1], vb, jbase0 + 32, tid);

  s16x8 pf0p, pf1p;
  {
    f32x16 sc = (f32x16)(0.f);
#pragma unroll
    for (int ks = 0; ks < 16; ++ks) {
      s16x8 kf = *(const s16x8*)(K_lds[0] + ks * 512 + (half * 32 + n32) * 8);
      sc = __builtin_amdgcn_mfma_f32_32x32x16_bf16(kf, qf[ks], sc, 0, 0, 0);
    }
    unsigned D[8], E[8];
#pragma unroll
    for (int t = 0; t < 8; ++t) {
      float pa = exp2f(fmaf(sc[2 * t],     1.44269504f, -11.54156032f));  // exp(s-8)
      float pb = exp2f(fmaf(sc[2 * t + 1], 1.44269504f, -11.54156032f));
      ls += pa + pb;
      D[t] = (__builtin_bit_cast(unsigned, pa) >> 16) |
             (__builtin_bit_cast(unsigned, pb) & 0xFFFF0000u);   // trunc pack
      E[t] = __shfl_xor(D[t], 32);
    }
    u32x4 w0 = {half ? E[2] : D[0], half ? E[3] : D[1],
                half ? D[2] : E[0], half ? D[3] : E[1]};   // j = 0..15
    u32x4 w1 = {half ? E[6] : D[4], half ? E[7] : D[5],
                half ? D[6] : E[4], half ? D[7] : E[5]};   // j = 16..31
    pf0p = __builtin_bit_cast(s16x8, w0);
    pf1p = __builtin_bit_cast(s16x8, w1);
  }

  int vr_i = 0, vw_i = 2;   // interval jt reads V[jt-1], writes V[jt+1]
  for (int jt = 1; jt < 32; ++jt) {
    __syncthreads();   // K[jt],V[jt] resident; all prior LDS reads done
    if (jt < 31) {
      int jb2 = jbase0 + (jt + 1) * 32;
      stage_K(K_lds[(jt + 1) & 1], kb, jb2, tid);
      stage_V(V_lds[vw_i], vb, jb2, tid);
    }
    const unsigned short* KT = K_lds[jt & 1];
    const unsigned short* VR = V_lds[vr_i];

    // ---- phase A: QK(jt) dependent chain interleaved with PV(jt-1) ----
    __builtin_amdgcn_s_setprio(1);
    f32x16 sc = (f32x16)(0.f);
#pragma unroll
    for (int ks = 0; ks < 16; ++ks) {
      s16x8 kf = *(const s16x8*)(KT + ks * 512 + (half * 32 + n32) * 8);
      sc = __builtin_amdgcn_mfma_f32_32x32x16_bf16(kf, qf[ks], sc, 0, 0, 0);
      if (ks < 8) {
        int ch = ks * 32 + n32;
        s16x8 vf0 = *(const s16x8*)(VR + (half * 256 + ch) * 8);
        s16x8 vf1 = *(const s16x8*)(VR + ((2 + half) * 256 + ch) * 8);
        Oa[ks] = __builtin_amdgcn_mfma_f32_32x32x16_bf16(pf0p, vf0, Oa[ks], 0, 0, 0);
        Oa[ks] = __builtin_amdgcn_mfma_f32_32x32x16_bf16(pf1p, vf1, Oa[ks], 0, 0, 0);
      }
    }
    __builtin_amdgcn_s_setprio(0);

    // ---- phase B: softmax(jt) -> new pf ----
    unsigned D[8], E[8];
#pragma unroll
    for (int t = 0; t < 8; ++t) {
      float pa = exp2f(fmaf(sc[2 * t],     1.44269504f, -11.54156032f));
      float pb = exp2f(fmaf(sc[2 * t + 1], 1.44269504f, -11.54156032f));
      ls += pa + pb;
      D[t] = (__builtin_bit_cast(unsigned, pa) >> 16) |
             (__builtin_bit_cast(unsigned, pb) & 0xFFFF0000u);
      E[t] = __shfl_xor(D[t], 32);
    }
    u32x4 w0 = {half ? E[2] : D[0], half ? E[3] : D[1],
                half ? D[2] : E[0], half ? D[3] : E[1]};
    u32x4 w1 = {half ? E[6] : D[4], half ? E[7] : D[5],
                half ? D[6] : E[4], half ? D[7] : E[5]};
    pf0p = __builtin_bit_cast(s16x8, w0);
    pf1p = __builtin_bit_cast(s16x8, w1);
    vr_i = (vr_i == 2) ? 0 : vr_i + 1;
    vw_i = (vw_i == 2) ? 0 : vw_i + 1;
  }

  // epilogue: PV(31) with the last pf (V[31] sits in V_lds[vr_i])
  {
    const unsigned short* VR = V_lds[vr_i];
#pragma unroll
    for (int t = 0; t < 8; ++t) {
      int ch = t * 32 + n32;
      s16x8 vf0 = *(const s16x8*)(VR + (half * 256 + ch) * 8);
      s16x8 vf1 = *(const s16x8*)(VR + ((2 + half) * 256 + ch) * 8);
      Oa[t] = __builtin_amdgcn_mfma_f32_32x32x16_bf16(pf0p, vf0, Oa[t], 0, 0, 0);
      Oa[t] = __builtin_amdgcn_mfma_f32_32x32x16_bf16(pf1p, vf1, Oa[t], 0, 0, 0);
    }
  }

#pragma unroll
  for (int ct = 0; ct < 8; ++ct)
#pragma unroll
    for (int r = 0; r < 16; ++r) {
      int row = (r & 3) + 8 * (r >> 2) + 4 * half;
      op[(size_t)(qrow0 + row) * C_DIM + ct * 32 + n32] = f2bf(Oa[ct][r]);
    }
  float tot = ls + __shfl_xor(ls, 32);
  if (half == 0) lbuf[chunk * M_ROWS + qrow0 + n32] = tot;
}

// ------- Output projection (fused combine) + bias + residual -> fp32 out ------
// row-split 64 rows/block, grid (256,2) = 2 blocks/CU; W DMA overlaps af build.
__global__ __launch_bounds__(256, 2) void proj_gemm(const unsigned short* __restrict__ p0,
                                                    const unsigned short* __restrict__ p1,
                                                    const unsigned short* __restrict__ p2,
                                                    const unsigned short* __restrict__ p3,
                                                    const float* __restrict__ lbuf,
                                                    const unsigned short* __restrict__ wt,
                                                    const float* __restrict__ bp,
                                                    const float* __restrict__ x,
                                                    float* __restrict__ out) {
  int tid = threadIdx.x;
  int wave = tid >> 6, lane = tid & 63, n32 = lane & 31, half = lane >> 5;
  int rg = wave >> 1, cv = wave & 1;
  int row0 = blockIdx.x * 64 + rg * 32;
  int c0 = blockIdx.y * 128;
  __shared__ __align__(16) unsigned short Wt[32768];   // 128 n x 256 k, swizzled

  stage_W(Wt, wt, c0, tid);

  int row = row0 + n32;
  float linv = 1.f / (lbuf[row] + lbuf[M_ROWS + row] +
                      lbuf[2 * M_ROWS + row] + lbuf[3 * M_ROWS + row]);
  s16x8 af[16];
#pragma unroll
  for (int ks = 0; ks < 16; ++ks) {
    size_t off = (size_t)row * C_DIM + ks * 16 + half * 8;
    s16x8 a0 = *(const s16x8*)(p0 + off);
    s16x8 a1 = *(const s16x8*)(p1 + off);
    s16x8 a2 = *(const s16x8*)(p2 + off);
    s16x8 a3 = *(const s16x8*)(p3 + off);
    s16x8 o;
#pragma unroll
    for (int j = 0; j < 8; ++j) {
      float f = bf2f((unsigned short)a0[j]) + bf2f((unsigned short)a1[j]) +
                bf2f((unsigned short)a2[j]) + bf2f((unsigned short)a3[j]);
      o[j] = (short)f2bf(f * linv);
    }
    af[ks] = o;
  }
  __syncthreads();   // W tile resident

#pragma unroll
  for (int ct = 0; ct < 2; ++ct) {
    int nl = (cv * 2 + ct) * 32 + n32;
    f32x16 acc = (f32x16)(bp[c0 + nl]);
#pragma unroll
    for (int ks = 0; ks < 16; ++ks) {
      s16x8 wf = *(const s16x8*)(Wt + nl * C_DIM + (((2 * ks + half) ^ (nl & 7)) * 8));
      acc = __builtin_amdgcn_mfma_f32_32x32x16_bf16(af[ks], wf, acc, 0, 0, 0);
    }
#pragma unroll
    for (int r = 0; r < 16; ++r) {
      int rr = (r & 3) + 8 * (r >> 2) + 4 * half;
      size_t idx = (size_t)(row0 + rr) * C_DIM + c0 + nl;
      out[idx] = acc[r] + x[idx];
    }
  }
}

extern "C" void kernel_launch(void* const* d_in, const int* in_sizes, int n_in,
                              void* d_out, int out_size, void* d_ws, size_t ws_size,
                              hipStream_t stream) {
  const float* x     = (const float*)d_in[0];
  const float* gamma = (const float*)d_in[1];
  const float* beta  = (const float*)d_in[2];
  const float* wq    = (const float*)d_in[3];
  const float* bq    = (const float*)d_in[4];
  const float* wk    = (const float*)d_in[5];
  const float* bk    = (const float*)d_in[6];
  const float* wv    = (const float*)d_in[7];
  const float* bv    = (const float*)d_in[8];
  const float* wp    = (const float*)d_in[9];
  const float* bp    = (const float*)d_in[10];
  float* out = (float*)d_out;

  char* ws = (char*)d_ws;
  const size_t MC = (size_t)M_ROWS * C_DIM;
  float* partials      = (float*)ws;                          // 512 x 2 floats (4 KB)
  unsigned short* wT   = (unsigned short*)(ws + 4096);        // 4 x 256x256 bf16
  unsigned short* qb   = wT + 4 * 65536;
  unsigned short* kbuf = qb + MC;
  unsigned short* vb   = kbuf + MC;                           // plane-1 alias
  unsigned short* vTb  = vb + MC;
  unsigned short* pl0  = vTb + MC;                            // O partial planes 0,2,3
  unsigned short* pl2  = pl0 + MC;
  unsigned short* pl3  = pl2 + MC;
  float* lbuf          = (float*)(pl3 + MC);                  // 4 x 16384 floats
  unsigned short* pl1  = vb;

  prep<<<768, 256, 0, stream>>>(x, wq, wk, wv, wp, partials, wT);
  qkv_gemm<<<dim3(256, 2), 256, 0, stream>>>(x, wT, partials, gamma, beta,
                                             bq, bk, bv, qb, kbuf, vTb);
  attn_part<<<512, 256, 0, stream>>>(qb, kbuf, vTb, pl0, pl1, pl2, pl3, lbuf);
  proj_gemm<<<dim3(256, 2), 256, 0, stream>>>(pl0, pl1, pl2, pl3, lbuf,
                                              wT + 3 * 65536, bp, x, out);
}

// Round 9
// 222.709 us; speedup vs baseline: 1.0074x; 1.0074x over previous
//
#include <hip/hip_runtime.h>

// Problem constants (B=4, H=W=64, C=256, GROUPS=8)
#define N_TOK 4096          // H*W
#define C_DIM 256
#define BATCH 4
#define M_ROWS (BATCH * N_TOK)   // 16384
#define GN_CNT 131072.0f         // 64*64*32 elements per (b, group)

typedef __attribute__((ext_vector_type(4))) float f32x4;
typedef __attribute__((ext_vector_type(16))) float f32x16;
typedef __attribute__((ext_vector_type(8))) short s16x8;      // 8 x bf16 (MFMA A/B frag)
typedef __attribute__((ext_vector_type(4))) unsigned short u16x4;
typedef __attribute__((ext_vector_type(4))) unsigned int u32x4;

static __device__ __forceinline__ unsigned short f2bf(float f) {
  unsigned int u = __builtin_bit_cast(unsigned int, f);
  u += 0x7fff + ((u >> 16) & 1);   // RNE
  return (unsigned short)(u >> 16);
}
static __device__ __forceinline__ float bf2f(unsigned short h) {
  unsigned int u = ((unsigned int)h) << 16;
  return __builtin_bit_cast(float, u);
}

// async global->LDS DMA, 16 B per lane; LDS dest = wave-uniform base + lane*16.
static __device__ __forceinline__ void gload_lds16(const void* g, void* l) {
  __builtin_amdgcn_global_load_lds(
      (__attribute__((address_space(1))) void*)(unsigned long long)(const char*)g,
      (__attribute__((address_space(3))) void*)l, 16, 0, 0);
}

// ---- prep: gn partial stats (blocks 0..511, no atomics) + wtrans (512..767) --
__global__ __launch_bounds__(256) void prep(const float* __restrict__ x,
                                            const float* __restrict__ wq,
                                            const float* __restrict__ wk,
                                            const float* __restrict__ wv,
                                            const float* __restrict__ wp,
                                            float* __restrict__ partials,
                                            unsigned short* __restrict__ wT) {
  int tid = threadIdx.x;
  if (blockIdx.x < 512) {
    // ---- GroupNorm partial stats: slot = (bg*16+chunk), overwrite (no init) --
    int bg = blockIdx.x >> 4, chunk = blockIdx.x & 15;
    int b = bg >> 3, g = bg & 7;
    const f32x4* x4 = (const f32x4*)x;
    float s1 = 0.f, s2 = 0.f;
#pragma unroll
    for (int it = 0; it < 8; ++it) {
      int idx = it * 256 + tid;
      int nl = idx >> 3, cq = idx & 7;
      f32x4 v = x4[(b * N_TOK + chunk * 256 + nl) * 64 + g * 8 + cq];
      s1 += v[0] + v[1] + v[2] + v[3];
      s2 += v[0] * v[0] + v[1] * v[1] + v[2] * v[2] + v[3] * v[3];
    }
    for (int m = 1; m < 64; m <<= 1) {
      s1 += __shfl_xor(s1, m, 64);
      s2 += __shfl_xor(s2, m, 64);
    }
    __shared__ float r1[4], r2[4];
    int wave = tid >> 6, lane = tid & 63;
    if (lane == 0) { r1[wave] = s1; r2[wave] = s2; }
    __syncthreads();
    if (tid == 0) {
      int slot = (bg * 16 + chunk) * 2;
      partials[slot]     = r1[0] + r1[1] + r1[2] + r1[3];
      partials[slot + 1] = r2[0] + r2[1] + r2[2] + r2[3];
    }
  } else {
    // ---- weight fp32 -> bf16 transposed: wT[n][k] = w[k][n] ----
    int rem = blockIdx.x - 512;
    int z = rem >> 6, t = rem & 63;
    int k0 = (t >> 3) * 32, n0 = (t & 7) * 32;
    const float* const srcs[4] = {wq, wk, wv, wp};
    const float* w = srcs[z];
    unsigned short* o = wT + z * 65536;
    __shared__ float tt[32][33];
    int tx = tid & 31, ty = tid >> 5;
#pragma unroll
    for (int ky = 0; ky < 32; ky += 8)
      tt[ty + ky][tx] = w[(k0 + ty + ky) * C_DIM + n0 + tx];
    __syncthreads();
#pragma unroll
    for (int ky = 0; ky < 32; ky += 8)
      o[(n0 + ty + ky) * C_DIM + k0 + tx] = f2bf(tt[tx][ty + ky]);
  }
}

// ---- W tile staging: 16 iters = 64 KB (128 n x 256 k bf16), src-swizzled ----
static __device__ __forceinline__ void stage_W(unsigned short* dst,
                                               const unsigned short* src,
                                               int c0, int tid) {
#pragma unroll
  for (int ii = 0; ii < 16; ++ii) {
    int u = ii * 256 + tid;
    int n = u >> 5, ku = u & 31;
    gload_lds16(src + (size_t)(c0 + n) * C_DIM + ((ku ^ (n & 7)) * 8), dst + u * 8);
  }
}

// ------ QKV GEMM, GroupNorm fused, V-transpose fused --------------------------
// v9 = v8 (kept): single-buffer W; GN stats per-wave via __shfl broadcast (no
// LDS/barrier dependency; af-build overlaps W(q) DMA). Measured ~12 us better
// non-attn than the tid<8+barrier variant (R6 114.8 -> R8 102.7).
__global__ __launch_bounds__(256, 2) void qkv_gemm(const float* __restrict__ x,
                                                   const unsigned short* __restrict__ wT,
                                                   const float* __restrict__ partials,
                                                   const float* __restrict__ gamma,
                                                   const float* __restrict__ beta,
                                                   const float* __restrict__ bq,
                                                   const float* __restrict__ bk,
                                                   const float* __restrict__ bv,
                                                   unsigned short* __restrict__ qo,
                                                   unsigned short* __restrict__ ko,
                                                   unsigned short* __restrict__ vTo) {
  int tid = threadIdx.x;
  int wave = tid >> 6, lane = tid & 63, n32 = lane & 31, half = lane >> 5;
  int rg = wave >> 1, cv = wave & 1;
  int row0 = blockIdx.x * 64 + rg * 32;
  int c0 = blockIdx.y * 128;
  int row = row0 + n32;
  int batch = blockIdx.x >> 6;               // 64 rowblocks per batch
  __shared__ __align__(16) unsigned short Wt[32768];   // 64 KB: one full W tile

  stage_W(Wt, wT, c0, tid);                  // W(q) in flight

  // per-wave GN stats, no barrier: lane computes group (lane&7), shfl broadcast
  float mean[8], rstd[8];
  {
    const float* p = partials + (batch * 8 + (lane & 7)) * 32;   // 16 chunks x 2
    float s1 = 0.f, s2 = 0.f;
#pragma unroll
    for (int c = 0; c < 16; ++c) { s1 += p[2 * c]; s2 += p[2 * c + 1]; }
    float inv = 1.f / GN_CNT;
    float m = s1 * inv, v = s2 * inv - m * m;
    float rs = rsqrtf(v + 1e-3f);
#pragma unroll
    for (int g = 0; g < 8; ++g) { mean[g] = __shfl(m, g); rstd[g] = __shfl(rs, g); }
  }

  // A-fragments: GroupNorm(x) inline, bf16-packed; k-unit = 2ks+half
  s16x8 af[16];
#pragma unroll
  for (int ks = 0; ks < 16; ++ks) {
    int cb = ks * 16 + half * 8;
    const f32x4* xp = (const f32x4*)(x + (size_t)row * C_DIM + cb);
    f32x4 v0 = xp[0], v1 = xp[1];
    const f32x4* g4 = (const f32x4*)(gamma + cb);
    const f32x4* b4 = (const f32x4*)(beta + cb);
    f32x4 ga0 = g4[0], ga1 = g4[1], be0 = b4[0], be1 = b4[1];
    int g = (2 * ks + half) >> 2;
    float m = mean[g], rs = rstd[g];
    s16x8 o;
#pragma unroll
    for (int j = 0; j < 4; ++j) {
      o[j]     = (short)f2bf((v0[j] - m) * rs * ga0[j] + be0[j]);
      o[4 + j] = (short)f2bf((v1[j] - m) * rs * ga1[j] + be1[j]);
    }
    af[ks] = o;
  }
  __syncthreads();   // W(q) resident

  f32x16 vacc[2];
  for (int w = 0; w < 3; ++w) {
    if (w > 0) {
      __syncthreads();   // previous W reads done
      stage_W(Wt, wT + (size_t)w * 65536, c0, tid);
      __syncthreads();   // new W resident
    }
    const float* bias = (w == 0) ? bq : (w == 1) ? bk : bv;
    unsigned short* outp = (w == 0) ? qo : ko;
    float scale = (w == 0) ? 0.0625f : 1.f;  // q absorbs softmax scale C^-0.5
#pragma unroll
    for (int ct = 0; ct < 2; ++ct) {
      int nl = (cv * 2 + ct) * 32 + n32;
      f32x16 acc = (f32x16)(bias[c0 + nl]);
#pragma unroll
      for (int ks = 0; ks < 16; ++ks) {
        s16x8 wf = *(const s16x8*)(Wt + nl * C_DIM + (((2 * ks + half) ^ (nl & 7)) * 8));
        acc = __builtin_amdgcn_mfma_f32_32x32x16_bf16(af[ks], wf, acc, 0, 0, 0);
      }
      if (w < 2) {
#pragma unroll
        for (int r = 0; r < 16; ++r) {
          int rr = (r & 3) + 8 * (r >> 2) + 4 * half;
          outp[(size_t)(row0 + rr) * C_DIM + c0 + nl] = f2bf(acc[r] * scale);
        }
      } else {
        vacc[ct] = acc;
      }
    }
  }

  // ---- fused V transpose: vacc -> Wt as [128 ch][72] -> coalesced vT stores --
  __syncthreads();                 // all Wt reads for w==2 complete
#pragma unroll
  for (int ct = 0; ct < 2; ++ct) {
    int ch = (cv * 2 + ct) * 32 + n32;
#pragma unroll
    for (int g = 0; g < 4; ++g) {
      u16x4 pk;
#pragma unroll
      for (int j = 0; j < 4; ++j) pk[j] = f2bf(vacc[ct][g * 4 + j]);
      int tok = rg * 32 + 8 * g + 4 * half;   // tokens within block (0..63)
      *(u16x4*)&Wt[ch * 72 + tok] = pk;
    }
  }
  __syncthreads();
  {
    int ch = tid >> 1, nh = tid & 1;          // 128 ch x 2 token-halves
    int tokb = (blockIdx.x & 63) * 64;        // token base within batch
    const u32x4* srcp = (const u32x4*)&Wt[ch * 72 + nh * 32];
    u32x4* dstp = (u32x4*)&vTo[((size_t)(batch * C_DIM + c0 + ch)) * N_TOK + tokb + nh * 32];
#pragma unroll
    for (int qq = 0; qq < 4; ++qq) dstp[qq] = srcp[qq];
  }
}

// ---- K staging: ks-major, lane-linear within ks block ------------------------
// QK read for lane (n32,half) at ks is byte ks*1024 + lane*16: each 16-lane
// quarter reads 256 B CONTIGUOUS -> zero bank conflicts (verified R5: 4.19M->0).
static __device__ __forceinline__ void stage_K(unsigned short* dst,
                                               const unsigned short* kb,
                                               int jbase, int tid) {
#pragma unroll
  for (int ii = 0; ii < 4; ++ii) {
    int u = ii * 256 + tid;
    int ksu = u >> 6, hf = (u >> 5) & 1, tok = u & 31;
    gload_lds16(kb + (size_t)(jbase + tok) * C_DIM + ksu * 16 + hf * 8, dst + u * 8);
  }
}
static __device__ __forceinline__ void stage_V(unsigned short* dst,
                                               const unsigned short* vb,
                                               int jbase, int tid) {
#pragma unroll
  for (int ii = 0; ii < 4; ++ii)
    gload_lds16(vb + (size_t)tid * N_TOK + jbase + ii * 8, dst + (ii * 256 + tid) * 8);
}

static __device__ __forceinline__ f32x16 qk_compute(const unsigned short* KT,
                                                    const s16x8* qf,
                                                    int n32, int half) {
  f32x16 sc = (f32x16)(0.f);
#pragma unroll
  for (int ks = 0; ks < 16; ++ks) {
    s16x8 kf = *(const s16x8*)(KT + ks * 512 + (half * 32 + n32) * 8);
    sc = __builtin_amdgcn_mfma_f32_32x32x16_bf16(kf, qf[ks], sc, 0, 0, 0);
  }
  return sc;
}

// ------- Flash attention partial: R6-exact structure (measured 104.6 us) ------
// Fused loop: QK(jt) MFMA block, then softmax(jt) VALU interleaved with
// PV(jt-1) MFMA+LDS in one t-loop. R8's QK||PV interleave regressed to 122 us
// (MfmaUtil 28->24: dual ds_read streams serialize on lgkmcnt, softmax ran
// bare) -> in-wave phase reordering closed, this arrangement is the optimum.
__global__ __launch_bounds__(256, 2) void attn_part(const unsigned short* __restrict__ q,
                                                    const unsigned short* __restrict__ k,
                                                    const unsigned short* __restrict__ vT,
                                                    unsigned short* __restrict__ op0,
                                                    unsigned short* __restrict__ op1,
                                                    unsigned short* __restrict__ op2,
                                                    unsigned short* __restrict__ op3,
                                                    float* __restrict__ lbuf) {
  int tid = threadIdx.x;
  int wave = tid >> 6, lane = tid & 63;
  int n32 = lane & 31, half = lane >> 5;
  int i = blockIdx.x;
  int batch = (i >> 1) & 3;
  int slot = ((i >> 3) << 1) | (i & 1);      // 0..127
  int qb = slot & 31, chunk = slot >> 5;     // 32 row-blocks x 4 chunks
  int qrow0 = batch * N_TOK + qb * 128 + wave * 32;
  const unsigned short* kb = k + (size_t)batch * N_TOK * C_DIM;
  const unsigned short* vb = vT + (size_t)batch * C_DIM * N_TOK;
  unsigned short* op = (chunk == 0) ? op0 : (chunk == 1) ? op1 : (chunk == 2) ? op2 : op3;

  __shared__ __align__(16) unsigned short K_lds[2][8192];  // ks-major, lane-linear
  __shared__ __align__(16) unsigned short V_lds[3][8192];  // jb-major: jb*256 + ch

  int jbase0 = chunk * 1024;
  stage_K(K_lds[0], kb, jbase0, tid);
  stage_V(V_lds[0], vb, jbase0, tid);

  const unsigned short* qp = q + (size_t)(qrow0 + n32) * C_DIM;
  s16x8 qf[16];
#pragma unroll
  for (int ks = 0; ks < 16; ++ks)
    qf[ks] = *(const s16x8*)(qp + ks * 16 + half * 8);

  f32x16 Oa[8];
#pragma unroll
  for (int ct = 0; ct < 8; ++ct) Oa[ct] = (f32x16)(0.f);
  float ls = 0.f;

  __syncthreads();   // tile 0 resident (drains qf loads too)

  // start tile 1 DMA, then compute QK(0) + softmax(0) -> pf persist regs
  stage_K(K_lds[1], kb, jbase0 + 32, tid);
  stage_V(V_lds[1], vb, jbase0 + 32, tid);

  s16x8 pf0p, pf1p;
  {
    f32x16 sc = qk_compute(K_lds[0], qf, n32, half);
    unsigned D[8], E[8];
#pragma unroll
    for (int t = 0; t < 8; ++t) {
      float pa = exp2f(fmaf(sc[2 * t],     1.44269504f, -11.54156032f));  // exp(s-8)
      float pb = exp2f(fmaf(sc[2 * t + 1], 1.44269504f, -11.54156032f));
      ls += pa + pb;
      D[t] = (__builtin_bit_cast(unsigned, pa) >> 16) |
             (__builtin_bit_cast(unsigned, pb) & 0xFFFF0000u);   // trunc pack
      E[t] = __shfl_xor(D[t], 32);
    }
    u32x4 w0 = {half ? E[2] : D[0], half ? E[3] : D[1],
                half ? D[2] : E[0], half ? D[3] : E[1]};   // j = 0..15
    u32x4 w1 = {half ? E[6] : D[4], half ? E[7] : D[5],
                half ? D[6] : E[4], half ? D[7] : E[5]};   // j = 16..31
    pf0p = __builtin_bit_cast(s16x8, w0);
    pf1p = __builtin_bit_cast(s16x8, w1);
  }

  int vr_i = 0, vw_i = 2;   // interval jt reads V[(jt-1)%3], writes V[(jt+1)%3]
  for (int jt = 1; jt < 32; ++jt) {
    __syncthreads();   // all waves done QK(jt-1)/PV(jt-2) reads; K[jt],V[jt] resident
    if (jt < 31) {
      int jb2 = jbase0 + (jt + 1) * 32;
      stage_K(K_lds[(jt + 1) & 1], kb, jb2, tid);
      stage_V(V_lds[vw_i], vb, jb2, tid);
    }
    __builtin_amdgcn_s_setprio(1);
    f32x16 sc = qk_compute(K_lds[jt & 1], qf, n32, half);

    // fused: softmax(jt) VALU interleaved with PV(jt-1) MFMA+LDS
    const unsigned short* VR = V_lds[vr_i];
    unsigned D[8], E[8];
#pragma unroll
    for (int t = 0; t < 8; ++t) {
      float pa = exp2f(fmaf(sc[2 * t],     1.44269504f, -11.54156032f));
      float pb = exp2f(fmaf(sc[2 * t + 1], 1.44269504f, -11.54156032f));
      ls += pa + pb;
      D[t] = (__builtin_bit_cast(unsigned, pa) >> 16) |
             (__builtin_bit_cast(unsigned, pb) & 0xFFFF0000u);
      E[t] = __shfl_xor(D[t], 32);
      int ch = t * 32 + n32;
      s16x8 vf0 = *(const s16x8*)(VR + (half * 256 + ch) * 8);
      s16x8 vf1 = *(const s16x8*)(VR + ((2 + half) * 256 + ch) * 8);
      Oa[t] = __builtin_amdgcn_mfma_f32_32x32x16_bf16(pf0p, vf0, Oa[t], 0, 0, 0);
      Oa[t] = __builtin_amdgcn_mfma_f32_32x32x16_bf16(pf1p, vf1, Oa[t], 0, 0, 0);
    }
    __builtin_amdgcn_s_setprio(0);

    u32x4 w0 = {half ? E[2] : D[0], half ? E[3] : D[1],
                half ? D[2] : E[0], half ? D[3] : E[1]};
    u32x4 w1 = {half ? E[6] : D[4], half ? E[7] : D[5],
                half ? D[6] : E[4], half ? D[7] : E[5]};
    pf0p = __builtin_bit_cast(s16x8, w0);
    pf1p = __builtin_bit_cast(s16x8, w1);
    vr_i = (vr_i == 2) ? 0 : vr_i + 1;
    vw_i = (vw_i == 2) ? 0 : vw_i + 1;
  }

  // epilogue: PV(31) with the last pf (V[31] sits in V_lds[vr_i])
  {
    const unsigned short* VR = V_lds[vr_i];
#pragma unroll
    for (int t = 0; t < 8; ++t) {
      int ch = t * 32 + n32;
      s16x8 vf0 = *(const s16x8*)(VR + (half * 256 + ch) * 8);
      s16x8 vf1 = *(const s16x8*)(VR + ((2 + half) * 256 + ch) * 8);
      Oa[t] = __builtin_amdgcn_mfma_f32_32x32x16_bf16(pf0p, vf0, Oa[t], 0, 0, 0);
      Oa[t] = __builtin_amdgcn_mfma_f32_32x32x16_bf16(pf1p, vf1, Oa[t], 0, 0, 0);
    }
  }

#pragma unroll
  for (int ct = 0; ct < 8; ++ct)
#pragma unroll
    for (int r = 0; r < 16; ++r) {
      int row = (r & 3) + 8 * (r >> 2) + 4 * half;
      op[(size_t)(qrow0 + row) * C_DIM + ct * 32 + n32] = f2bf(Oa[ct][r]);
    }
  float tot = ls + __shfl_xor(ls, 32);
  if (half == 0) lbuf[chunk * M_ROWS + qrow0 + n32] = tot;
}

// ------- Output projection (fused combine) + bias + residual -> fp32 out ------
// row-split 64 rows/block, grid (256,2) = 2 blocks/CU; W DMA overlaps af build.
__global__ __launch_bounds__(256, 2) void proj_gemm(const unsigned short* __restrict__ p0,
                                                    const unsigned short* __restrict__ p1,
                                                    const unsigned short* __restrict__ p2,
                                                    const unsigned short* __restrict__ p3,
                                                    const float* __restrict__ lbuf,
                                                    const unsigned short* __restrict__ wt,
                                                    const float* __restrict__ bp,
                                                    const float* __restrict__ x,
                                                    float* __restrict__ out) {
  int tid = threadIdx.x;
  int wave = tid >> 6, lane = tid & 63, n32 = lane & 31, half = lane >> 5;
  int rg = wave >> 1, cv = wave & 1;
  int row0 = blockIdx.x * 64 + rg * 32;
  int c0 = blockIdx.y * 128;
  __shared__ __align__(16) unsigned short Wt[32768];   // 128 n x 256 k, swizzled

  stage_W(Wt, wt, c0, tid);

  int row = row0 + n32;
  float linv = 1.f / (lbuf[row] + lbuf[M_ROWS + row] +
                      lbuf[2 * M_ROWS + row] + lbuf[3 * M_ROWS + row]);
  s16x8 af[16];
#pragma unroll
  for (int ks = 0; ks < 16; ++ks) {
    size_t off = (size_t)row * C_DIM + ks * 16 + half * 8;
    s16x8 a0 = *(const s16x8*)(p0 + off);
    s16x8 a1 = *(const s16x8*)(p1 + off);
    s16x8 a2 = *(const s16x8*)(p2 + off);
    s16x8 a3 = *(const s16x8*)(p3 + off);
    s16x8 o;
#pragma unroll
    for (int j = 0; j < 8; ++j) {
      float f = bf2f((unsigned short)a0[j]) + bf2f((unsigned short)a1[j]) +
                bf2f((unsigned short)a2[j]) + bf2f((unsigned short)a3[j]);
      o[j] = (short)f2bf(f * linv);
    }
    af[ks] = o;
  }
  __syncthreads();   // W tile resident

#pragma unroll
  for (int ct = 0; ct < 2; ++ct) {
    int nl = (cv * 2 + ct) * 32 + n32;
    f32x16 acc = (f32x16)(bp[c0 + nl]);
#pragma unroll
    for (int ks = 0; ks < 16; ++ks) {
      s16x8 wf = *(const s16x8*)(Wt + nl * C_DIM + (((2 * ks + half) ^ (nl & 7)) * 8));
      acc = __builtin_amdgcn_mfma_f32_32x32x16_bf16(af[ks], wf, acc, 0, 0, 0);
    }
#pragma unroll
    for (int r = 0; r < 16; ++r) {
      int rr = (r & 3) + 8 * (r >> 2) + 4 * half;
      size_t idx = (size_t)(row0 + rr) * C_DIM + c0 + nl;
      out[idx] = acc[r] + x[idx];
    }
  }
}

extern "C" void kernel_launch(void* const* d_in, const int* in_sizes, int n_in,
                              void* d_out, int out_size, void* d_ws, size_t ws_size,
                              hipStream_t stream) {
  const float* x     = (const float*)d_in[0];
  const float* gamma = (const float*)d_in[1];
  const float* beta  = (const float*)d_in[2];
  const float* wq    = (const float*)d_in[3];
  const float* bq    = (const float*)d_in[4];
  const float* wk    = (const float*)d_in[5];
  const float* bk    = (const float*)d_in[6];
  const float* wv    = (const float*)d_in[7];
  const float* bv    = (const float*)d_in[8];
  const float* wp    = (const float*)d_in[9];
  const float* bp    = (const float*)d_in[10];
  float* out = (float*)d_out;

  char* ws = (char*)d_ws;
  const size_t MC = (size_t)M_ROWS * C_DIM;
  float* partials      = (float*)ws;                          // 512 x 2 floats (4 KB)
  unsigned short* wT   = (unsigned short*)(ws + 4096);        // 4 x 256x256 bf16
  unsigned short* qb   = wT + 4 * 65536;
  unsigned short* kbuf = qb + MC;
  unsigned short* vb   = kbuf + MC;                           // plane-1 alias
  unsigned short* vTb  = vb + MC;
  unsigned short* pl0  = vTb + MC;                            // O partial planes 0,2,3
  unsigned short* pl2  = pl0 + MC;
  unsigned short* pl3  = pl2 + MC;
  float* lbuf          = (float*)(pl3 + MC);                  // 4 x 16384 floats
  unsigned short* pl1  = vb;

  prep<<<768, 256, 0, stream>>>(x, wq, wk, wv, wp, partials, wT);
  qkv_gemm<<<dim3(256, 2), 256, 0, stream>>>(x, wT, partials, gamma, beta,
                                             bq, bk, bv, qb, kbuf, vTb);
  attn_part<<<512, 256, 0, stream>>>(qb, kbuf, vTb, pl0, pl1, pl2, pl3, lbuf);
  proj_gemm<<<dim3(256, 2), 256, 0, stream>>>(pl0, pl1, pl2, pl3, lbuf,
                                              wT + 3 * 65536, bp, x, out);
}

// Round 11
// 216.776 us; speedup vs baseline: 1.0350x; 1.0274x over previous
//
#include <hip/hip_runtime.h>

// Problem constants (B=4, H=W=64, C=256, GROUPS=8)
#define N_TOK 4096          // H*W
#define C_DIM 256
#define BATCH 4
#define M_ROWS (BATCH * N_TOK)   // 16384
#define GN_CNT 131072.0f         // 64*64*32 elements per (b, group)

typedef __attribute__((ext_vector_type(4))) float f32x4;
typedef __attribute__((ext_vector_type(16))) float f32x16;
typedef __attribute__((ext_vector_type(8))) short s16x8;      // 8 x bf16 (MFMA A/B frag)
typedef __attribute__((ext_vector_type(4))) unsigned short u16x4;
typedef __attribute__((ext_vector_type(4))) unsigned int u32x4;

static __device__ __forceinline__ unsigned short f2bf(float f) {
  unsigned int u = __builtin_bit_cast(unsigned int, f);
  u += 0x7fff + ((u >> 16) & 1);   // RNE
  return (unsigned short)(u >> 16);
}
static __device__ __forceinline__ float bf2f(unsigned short h) {
  unsigned int u = ((unsigned int)h) << 16;
  return __builtin_bit_cast(float, u);
}

// async global->LDS DMA, 16 B per lane; LDS dest = wave-uniform base + lane*16.
static __device__ __forceinline__ void gload_lds16(const void* g, void* l) {
  __builtin_amdgcn_global_load_lds(
      (__attribute__((address_space(1))) void*)(unsigned long long)(const char*)g,
      (__attribute__((address_space(3))) void*)l, 16, 0, 0);
}

// ---- prep: gn partial stats (blocks 0..511, no atomics) + wtrans (512..767) --
__global__ __launch_bounds__(256) void prep(const float* __restrict__ x,
                                            const float* __restrict__ wq,
                                            const float* __restrict__ wk,
                                            const float* __restrict__ wv,
                                            const float* __restrict__ wp,
                                            float* __restrict__ partials,
                                            unsigned short* __restrict__ wT) {
  int tid = threadIdx.x;
  if (blockIdx.x < 512) {
    // ---- GroupNorm partial stats: slot = (bg*16+chunk), overwrite (no init) --
    int bg = blockIdx.x >> 4, chunk = blockIdx.x & 15;
    int b = bg >> 3, g = bg & 7;
    const f32x4* x4 = (const f32x4*)x;
    float s1 = 0.f, s2 = 0.f;
#pragma unroll
    for (int it = 0; it < 8; ++it) {
      int idx = it * 256 + tid;
      int nl = idx >> 3, cq = idx & 7;
      f32x4 v = x4[(b * N_TOK + chunk * 256 + nl) * 64 + g * 8 + cq];
      s1 += v[0] + v[1] + v[2] + v[3];
      s2 += v[0] * v[0] + v[1] * v[1] + v[2] * v[2] + v[3] * v[3];
    }
    for (int m = 1; m < 64; m <<= 1) {
      s1 += __shfl_xor(s1, m, 64);
      s2 += __shfl_xor(s2, m, 64);
    }
    __shared__ float r1[4], r2[4];
    int wave = tid >> 6, lane = tid & 63;
    if (lane == 0) { r1[wave] = s1; r2[wave] = s2; }
    __syncthreads();
    if (tid == 0) {
      int slot = (bg * 16 + chunk) * 2;
      partials[slot]     = r1[0] + r1[1] + r1[2] + r1[3];
      partials[slot + 1] = r2[0] + r2[1] + r2[2] + r2[3];
    }
  } else {
    // ---- weight fp32 -> bf16 transposed: wT[n][k] = w[k][n] ----
    int rem = blockIdx.x - 512;
    int z = rem >> 6, t = rem & 63;
    int k0 = (t >> 3) * 32, n0 = (t & 7) * 32;
    const float* const srcs[4] = {wq, wk, wv, wp};
    const float* w = srcs[z];
    unsigned short* o = wT + z * 65536;
    __shared__ float tt[32][33];
    int tx = tid & 31, ty = tid >> 5;
#pragma unroll
    for (int ky = 0; ky < 32; ky += 8)
      tt[ty + ky][tx] = w[(k0 + ty + ky) * C_DIM + n0 + tx];
    __syncthreads();
#pragma unroll
    for (int ky = 0; ky < 32; ky += 8)
      o[(n0 + ty + ky) * C_DIM + k0 + tx] = f2bf(tt[tx][ty + ky]);
  }
}

// ---- W tile staging: 16 iters = 64 KB (128 n x 256 k bf16), src-swizzled ----
static __device__ __forceinline__ void stage_W(unsigned short* dst,
                                               const unsigned short* src,
                                               int c0, int tid) {
#pragma unroll
  for (int ii = 0; ii < 16; ++ii) {
    int u = ii * 256 + tid;
    int n = u >> 5, ku = u & 31;
    gload_lds16(src + (size_t)(c0 + n) * C_DIM + ((ku ^ (n & 7)) * 8), dst + u * 8);
  }
}

// ------ QKV GEMM, GroupNorm fused, V-transpose fused --------------------------
// v11 = v10 with the bv shadowing fix. Load-ISSUE-ORDER fix: VMEM ops retire
// in issue order, so any load issued AFTER stage_W's 16 DMA cannot be consumed
// until the whole 64 KB W drains -- the previous af-build never actually
// overlapped the DMA. Now all af inputs (gamma/beta->LDS, x->regs,
// stats->regs) are issued BEFORE the DMA (pinned by sched_barrier), so GN/pack
// VALU runs under the W(q) transfer. gamma/beta visibility uses a raw
// s_barrier + lgkmcnt(0) (no vmcnt drain).
__global__ __launch_bounds__(256, 2) void qkv_gemm(const float* __restrict__ x,
                                                   const unsigned short* __restrict__ wT,
                                                   const float* __restrict__ partials,
                                                   const float* __restrict__ gamma,
                                                   const float* __restrict__ beta,
                                                   const float* __restrict__ bq,
                                                   const float* __restrict__ bk,
                                                   const float* __restrict__ bv,
                                                   unsigned short* __restrict__ qo,
                                                   unsigned short* __restrict__ ko,
                                                   unsigned short* __restrict__ vTo) {
  int tid = threadIdx.x;
  int wave = tid >> 6, lane = tid & 63, n32 = lane & 31, half = lane >> 5;
  int rg = wave >> 1, cv = wave & 1;
  int row0 = blockIdx.x * 64 + rg * 32;
  int c0 = blockIdx.y * 128;
  int row = row0 + n32;
  int batch = blockIdx.x >> 6;               // 64 rowblocks per batch
  __shared__ __align__(16) unsigned short Wt[32768];   // 64 KB: one full W tile
  __shared__ float gb_lds[512];                        // gamma[256], beta[256]

  // ---- (1) all af-build loads, issued BEFORE the W DMA ----
  float gvv = gamma[tid], bvv = beta[tid];
  f32x4 xv0[16], xv1[16];
  {
    const f32x4* xp = (const f32x4*)(x + (size_t)row * C_DIM);
#pragma unroll
    for (int ks = 0; ks < 16; ++ks) {
      int cb4 = (ks * 16 + half * 8) >> 2;
      xv0[ks] = xp[cb4];
      xv1[ks] = xp[cb4 + 1];
    }
  }
  f32x4 ps[8];
  {
    const f32x4* p4 = (const f32x4*)(partials + (batch * 8 + (lane & 7)) * 32);
#pragma unroll
    for (int c = 0; c < 8; ++c) ps[c] = p4[c];
  }
  __builtin_amdgcn_sched_barrier(0);         // pin: loads above, DMA below

  // ---- (2) W(q) DMA ----
  stage_W(Wt, wT, c0, tid);

  // ---- (3) VALU under the DMA ----
  gb_lds[tid] = gvv;
  gb_lds[256 + tid] = bvv;
  float mean[8], rstd[8];
  {
    float s1 = 0.f, s2 = 0.f;
#pragma unroll
    for (int c = 0; c < 8; ++c) {
      s1 += ps[c][0] + ps[c][2];
      s2 += ps[c][1] + ps[c][3];
    }
    float inv = 1.f / GN_CNT;
    float m = s1 * inv, v = s2 * inv - m * m;
    float rs = rsqrtf(v + 1e-3f);
#pragma unroll
    for (int g = 0; g < 8; ++g) { mean[g] = __shfl(m, g); rstd[g] = __shfl(rs, g); }
  }
  // gb visible to all waves: raw barrier, LDS-count drain only (DMA stays live)
  asm volatile("s_waitcnt lgkmcnt(0)" ::: "memory");
  __builtin_amdgcn_s_barrier();
  __builtin_amdgcn_sched_barrier(0);

  // A-fragments: GroupNorm(x) inline, bf16-packed; k-unit = 2ks+half
  s16x8 af[16];
#pragma unroll
  for (int ks = 0; ks < 16; ++ks) {
    int cb = ks * 16 + half * 8;
    f32x4 v0 = xv0[ks], v1 = xv1[ks];
    f32x4 ga0 = *(const f32x4*)&gb_lds[cb];
    f32x4 ga1 = *(const f32x4*)&gb_lds[cb + 4];
    f32x4 be0 = *(const f32x4*)&gb_lds[256 + cb];
    f32x4 be1 = *(const f32x4*)&gb_lds[256 + cb + 4];
    int g = (2 * ks + half) >> 2;
    float m = mean[g], rs = rstd[g];
    s16x8 o;
#pragma unroll
    for (int j = 0; j < 4; ++j) {
      o[j]     = (short)f2bf((v0[j] - m) * rs * ga0[j] + be0[j]);
      o[4 + j] = (short)f2bf((v1[j] - m) * rs * ga1[j] + be1[j]);
    }
    af[ks] = o;
  }
  __syncthreads();   // W(q) resident (drains DMA; af-build already done)

  f32x16 vacc[2];
  for (int w = 0; w < 3; ++w) {
    if (w > 0) {
      __syncthreads();   // previous W reads done
      stage_W(Wt, wT + (size_t)w * 65536, c0, tid);
      __syncthreads();   // new W resident
    }
    const float* bias = (w == 0) ? bq : (w == 1) ? bk : bv;
    unsigned short* outp = (w == 0) ? qo : ko;
    float scale = (w == 0) ? 0.0625f : 1.f;  // q absorbs softmax scale C^-0.5
#pragma unroll
    for (int ct = 0; ct < 2; ++ct) {
      int nl = (cv * 2 + ct) * 32 + n32;
      f32x16 acc = (f32x16)(bias[c0 + nl]);
#pragma unroll
      for (int ks = 0; ks < 16; ++ks) {
        s16x8 wf = *(const s16x8*)(Wt + nl * C_DIM + (((2 * ks + half) ^ (nl & 7)) * 8));
        acc = __builtin_amdgcn_mfma_f32_32x32x16_bf16(af[ks], wf, acc, 0, 0, 0);
      }
      if (w < 2) {
#pragma unroll
        for (int r = 0; r < 16; ++r) {
          int rr = (r & 3) + 8 * (r >> 2) + 4 * half;
          outp[(size_t)(row0 + rr) * C_DIM + c0 + nl] = f2bf(acc[r] * scale);
        }
      } else {
        vacc[ct] = acc;
      }
    }
  }

  // ---- fused V transpose: vacc -> Wt as [128 ch][72] -> coalesced vT stores --
  __syncthreads();                 // all Wt reads for w==2 complete
#pragma unroll
  for (int ct = 0; ct < 2; ++ct) {
    int ch = (cv * 2 + ct) * 32 + n32;
#pragma unroll
    for (int g = 0; g < 4; ++g) {
      u16x4 pk;
#pragma unroll
      for (int j = 0; j < 4; ++j) pk[j] = f2bf(vacc[ct][g * 4 + j]);
      int tok = rg * 32 + 8 * g + 4 * half;   // tokens within block (0..63)
      *(u16x4*)&Wt[ch * 72 + tok] = pk;
    }
  }
  __syncthreads();
  {
    int ch = tid >> 1, nh = tid & 1;          // 128 ch x 2 token-halves
    int tokb = (blockIdx.x & 63) * 64;        // token base within batch
    const u32x4* srcp = (const u32x4*)&Wt[ch * 72 + nh * 32];
    u32x4* dstp = (u32x4*)&vTo[((size_t)(batch * C_DIM + c0 + ch)) * N_TOK + tokb + nh * 32];
#pragma unroll
    for (int qq = 0; qq < 4; ++qq) dstp[qq] = srcp[qq];
  }
}

// ---- K staging: ks-major, lane-linear within ks block ------------------------
// QK read for lane (n32,half) at ks is byte ks*1024 + lane*16: each 16-lane
// quarter reads 256 B CONTIGUOUS -> zero bank conflicts (verified R5: 4.19M->0).
static __device__ __forceinline__ void stage_K(unsigned short* dst,
                                               const unsigned short* kb,
                                               int jbase, int tid) {
#pragma unroll
  for (int ii = 0; ii < 4; ++ii) {
    int u = ii * 256 + tid;
    int ksu = u >> 6, hf = (u >> 5) & 1, tok = u & 31;
    gload_lds16(kb + (size_t)(jbase + tok) * C_DIM + ksu * 16 + hf * 8, dst + u * 8);
  }
}
static __device__ __forceinline__ void stage_V(unsigned short* dst,
                                               const unsigned short* vb,
                                               int jbase, int tid) {
#pragma unroll
  for (int ii = 0; ii < 4; ++ii)
    gload_lds16(vb + (size_t)tid * N_TOK + jbase + ii * 8, dst + (ii * 256 + tid) * 8);
}

static __device__ __forceinline__ f32x16 qk_compute(const unsigned short* KT,
                                                    const s16x8* qf,
                                                    int n32, int half) {
  f32x16 sc = (f32x16)(0.f);
#pragma unroll
  for (int ks = 0; ks < 16; ++ks) {
    s16x8 kf = *(const s16x8*)(KT + ks * 512 + (half * 32 + n32) * 8);
    sc = __builtin_amdgcn_mfma_f32_32x32x16_bf16(kf, qf[ks], sc, 0, 0, 0);
  }
  return sc;
}

// ------- Flash attention partial: R6-exact structure (104.5 us, reproduced) ---
// Fused loop: QK(jt) MFMA block, then softmax(jt) VALU interleaved with
// PV(jt-1) MFMA+LDS. V triple-buffer, K double. One syncthreads/jt. Closed:
// R8's QK||PV interleave regressed (24% MfmaUtil); this arrangement is optimal
// at the structural 2-waves/SIMD register cap (Oa 128 AGPR + qf 64 VGPR).
__global__ __launch_bounds__(256, 2) void attn_part(const unsigned short* __restrict__ q,
                                                    const unsigned short* __restrict__ k,
                                                    const unsigned short* __restrict__ vT,
                                                    unsigned short* __restrict__ op0,
                                                    unsigned short* __restrict__ op1,
                                                    unsigned short* __restrict__ op2,
                                                    unsigned short* __restrict__ op3,
                                                    float* __restrict__ lbuf) {
  int tid = threadIdx.x;
  int wave = tid >> 6, lane = tid & 63;
  int n32 = lane & 31, half = lane >> 5;
  int i = blockIdx.x;
  int batch = (i >> 1) & 3;
  int slot = ((i >> 3) << 1) | (i & 1);      // 0..127
  int qb = slot & 31, chunk = slot >> 5;     // 32 row-blocks x 4 chunks
  int qrow0 = batch * N_TOK + qb * 128 + wave * 32;
  const unsigned short* kb = k + (size_t)batch * N_TOK * C_DIM;
  const unsigned short* vb = vT + (size_t)batch * C_DIM * N_TOK;
  unsigned short* op = (chunk == 0) ? op0 : (chunk == 1) ? op1 : (chunk == 2) ? op2 : op3;

  __shared__ __align__(16) unsigned short K_lds[2][8192];  // ks-major, lane-linear
  __shared__ __align__(16) unsigned short V_lds[3][8192];  // jb-major: jb*256 + ch

  int jbase0 = chunk * 1024;
  stage_K(K_lds[0], kb, jbase0, tid);
  stage_V(V_lds[0], vb, jbase0, tid);

  const unsigned short* qp = q + (size_t)(qrow0 + n32) * C_DIM;
  s16x8 qf[16];
#pragma unroll
  for (int ks = 0; ks < 16; ++ks)
    qf[ks] = *(const s16x8*)(qp + ks * 16 + half * 8);

  f32x16 Oa[8];
#pragma unroll
  for (int ct = 0; ct < 8; ++ct) Oa[ct] = (f32x16)(0.f);
  float ls = 0.f;

  __syncthreads();   // tile 0 resident (drains qf loads too)

  // start tile 1 DMA, then compute QK(0) + softmax(0) -> pf persist regs
  stage_K(K_lds[1], kb, jbase0 + 32, tid);
  stage_V(V_lds[1], vb, jbase0 + 32, tid);

  s16x8 pf0p, pf1p;
  {
    f32x16 sc = qk_compute(K_lds[0], qf, n32, half);
    unsigned D[8], E[8];
#pragma unroll
    for (int t = 0; t < 8; ++t) {
      float pa = exp2f(fmaf(sc[2 * t],     1.44269504f, -11.54156032f));  // exp(s-8)
      float pb = exp2f(fmaf(sc[2 * t + 1], 1.44269504f, -11.54156032f));
      ls += pa + pb;
      D[t] = (__builtin_bit_cast(unsigned, pa) >> 16) |
             (__builtin_bit_cast(unsigned, pb) & 0xFFFF0000u);   // trunc pack
      E[t] = __shfl_xor(D[t], 32);
    }
    u32x4 w0 = {half ? E[2] : D[0], half ? E[3] : D[1],
                half ? D[2] : E[0], half ? D[3] : E[1]};   // j = 0..15
    u32x4 w1 = {half ? E[6] : D[4], half ? E[7] : D[5],
                half ? D[6] : E[4], half ? D[7] : E[5]};   // j = 16..31
    pf0p = __builtin_bit_cast(s16x8, w0);
    pf1p = __builtin_bit_cast(s16x8, w1);
  }

  int vr_i = 0, vw_i = 2;   // interval jt reads V[(jt-1)%3], writes V[(jt+1)%3]
  for (int jt = 1; jt < 32; ++jt) {
    __syncthreads();   // all waves done QK(jt-1)/PV(jt-2) reads; K[jt],V[jt] resident
    if (jt < 31) {
      int jb2 = jbase0 + (jt + 1) * 32;
      stage_K(K_lds[(jt + 1) & 1], kb, jb2, tid);
      stage_V(V_lds[vw_i], vb, jb2, tid);
    }
    __builtin_amdgcn_s_setprio(1);
    f32x16 sc = qk_compute(K_lds[jt & 1], qf, n32, half);

    // fused: softmax(jt) VALU interleaved with PV(jt-1) MFMA+LDS
    const unsigned short* VR = V_lds[vr_i];
    unsigned D[8], E[8];
#pragma unroll
    for (int t = 0; t < 8; ++t) {
      float pa = exp2f(fmaf(sc[2 * t],     1.44269504f, -11.54156032f));
      float pb = exp2f(fmaf(sc[2 * t + 1], 1.44269504f, -11.54156032f));
      ls += pa + pb;
      D[t] = (__builtin_bit_cast(unsigned, pa) >> 16) |
             (__builtin_bit_cast(unsigned, pb) & 0xFFFF0000u);
      E[t] = __shfl_xor(D[t], 32);
      int ch = t * 32 + n32;
      s16x8 vf0 = *(const s16x8*)(VR + (half * 256 + ch) * 8);
      s16x8 vf1 = *(const s16x8*)(VR + ((2 + half) * 256 + ch) * 8);
      Oa[t] = __builtin_amdgcn_mfma_f32_32x32x16_bf16(pf0p, vf0, Oa[t], 0, 0, 0);
      Oa[t] = __builtin_amdgcn_mfma_f32_32x32x16_bf16(pf1p, vf1, Oa[t], 0, 0, 0);
    }
    __builtin_amdgcn_s_setprio(0);

    u32x4 w0 = {half ? E[2] : D[0], half ? E[3] : D[1],
                half ? D[2] : E[0], half ? D[3] : E[1]};
    u32x4 w1 = {half ? E[6] : D[4], half ? E[7] : D[5],
                half ? D[6] : E[4], half ? D[7] : E[5]};
    pf0p = __builtin_bit_cast(s16x8, w0);
    pf1p = __builtin_bit_cast(s16x8, w1);
    vr_i = (vr_i == 2) ? 0 : vr_i + 1;
    vw_i = (vw_i == 2) ? 0 : vw_i + 1;
  }

  // epilogue: PV(31) with the last pf (V[31] sits in V_lds[vr_i])
  {
    const unsigned short* VR = V_lds[vr_i];
#pragma unroll
    for (int t = 0; t < 8; ++t) {
      int ch = t * 32 + n32;
      s16x8 vf0 = *(const s16x8*)(VR + (half * 256 + ch) * 8);
      s16x8 vf1 = *(const s16x8*)(VR + ((2 + half) * 256 + ch) * 8);
      Oa[t] = __builtin_amdgcn_mfma_f32_32x32x16_bf16(pf0p, vf0, Oa[t], 0, 0, 0);
      Oa[t] = __builtin_amdgcn_mfma_f32_32x32x16_bf16(pf1p, vf1, Oa[t], 0, 0, 0);
    }
  }

#pragma unroll
  for (int ct = 0; ct < 8; ++ct)
#pragma unroll
    for (int r = 0; r < 16; ++r) {
      int row = (r & 3) + 8 * (r >> 2) + 4 * half;
      op[(size_t)(qrow0 + row) * C_DIM + ct * 32 + n32] = f2bf(Oa[ct][r]);
    }
  float tot = ls + __shfl_xor(ls, 32);
  if (half == 0) lbuf[chunk * M_ROWS + qrow0 + n32] = tot;
}

// ------- Output projection (fused combine) + bias + residual -> fp32 out ------
// v11: plane loads for ks 0-7 + lbuf hoisted ahead of the W DMA (issue-order
// fix; ks 8-15 remain behind -> partial overlap, full hoist would need 256 regs).
__global__ __launch_bounds__(256, 2) void proj_gemm(const unsigned short* __restrict__ p0,
                                                    const unsigned short* __restrict__ p1,
                                                    const unsigned short* __restrict__ p2,
                                                    const unsigned short* __restrict__ p3,
                                                    const float* __restrict__ lbuf,
                                                    const unsigned short* __restrict__ wt,
                                                    const float* __restrict__ bp,
                                                    const float* __restrict__ x,
                                                    float* __restrict__ out) {
  int tid = threadIdx.x;
  int wave = tid >> 6, lane = tid & 63, n32 = lane & 31, half = lane >> 5;
  int rg = wave >> 1, cv = wave & 1;
  int row0 = blockIdx.x * 64 + rg * 32;
  int c0 = blockIdx.y * 128;
  int row = row0 + n32;
  __shared__ __align__(16) unsigned short Wt[32768];   // 128 n x 256 k, swizzled

  // ---- loads issued BEFORE the W DMA ----
  float l0 = lbuf[row], l1 = lbuf[M_ROWS + row],
        l2 = lbuf[2 * M_ROWS + row], l3 = lbuf[3 * M_ROWS + row];
  s16x8 h0[8], h1[8], h2[8], h3[8];
  {
    size_t base = (size_t)row * C_DIM + half * 8;
#pragma unroll
    for (int ks = 0; ks < 8; ++ks) {
      size_t off = base + ks * 16;
      h0[ks] = *(const s16x8*)(p0 + off);
      h1[ks] = *(const s16x8*)(p1 + off);
      h2[ks] = *(const s16x8*)(p2 + off);
      h3[ks] = *(const s16x8*)(p3 + off);
    }
  }
  __builtin_amdgcn_sched_barrier(0);         // pin: loads above, DMA below

  stage_W(Wt, wt, c0, tid);

  float linv = 1.f / (l0 + l1 + l2 + l3);
  s16x8 af[16];
#pragma unroll
  for (int ks = 0; ks < 8; ++ks) {
    s16x8 o;
#pragma unroll
    for (int j = 0; j < 8; ++j) {
      float f = bf2f((unsigned short)h0[ks][j]) + bf2f((unsigned short)h1[ks][j]) +
                bf2f((unsigned short)h2[ks][j]) + bf2f((unsigned short)h3[ks][j]);
      o[j] = (short)f2bf(f * linv);
    }
    af[ks] = o;
  }
#pragma unroll
  for (int ks = 8; ks < 16; ++ks) {
    size_t off = (size_t)row * C_DIM + ks * 16 + half * 8;
    s16x8 a0 = *(const s16x8*)(p0 + off);
    s16x8 a1 = *(const s16x8*)(p1 + off);
    s16x8 a2 = *(const s16x8*)(p2 + off);
    s16x8 a3 = *(const s16x8*)(p3 + off);
    s16x8 o;
#pragma unroll
    for (int j = 0; j < 8; ++j) {
      float f = bf2f((unsigned short)a0[j]) + bf2f((unsigned short)a1[j]) +
                bf2f((unsigned short)a2[j]) + bf2f((unsigned short)a3[j]);
      o[j] = (short)f2bf(f * linv);
    }
    af[ks] = o;
  }
  __syncthreads();   // W tile resident

#pragma unroll
  for (int ct = 0; ct < 2; ++ct) {
    int nl = (cv * 2 + ct) * 32 + n32;
    f32x16 acc = (f32x16)(bp[c0 + nl]);
#pragma unroll
    for (int ks = 0; ks < 16; ++ks) {
      s16x8 wf = *(const s16x8*)(Wt + nl * C_DIM + (((2 * ks + half) ^ (nl & 7)) * 8));
      acc = __builtin_amdgcn_mfma_f32_32x32x16_bf16(af[ks], wf, acc, 0, 0, 0);
    }
#pragma unroll
    for (int r = 0; r < 16; ++r) {
      int rr = (r & 3) + 8 * (r >> 2) + 4 * half;
      size_t idx = (size_t)(row0 + rr) * C_DIM + c0 + nl;
      out[idx] = acc[r] + x[idx];
    }
  }
}

extern "C" void kernel_launch(void* const* d_in, const int* in_sizes, int n_in,
                              void* d_out, int out_size, void* d_ws, size_t ws_size,
                              hipStream_t stream) {
  const float* x     = (const float*)d_in[0];
  const float* gamma = (const float*)d_in[1];
  const float* beta  = (const float*)d_in[2];
  const float* wq    = (const float*)d_in[3];
  const float* bq    = (const float*)d_in[4];
  const float* wk    = (const float*)d_in[5];
  const float* bk    = (const float*)d_in[6];
  const float* wv    = (const float*)d_in[7];
  const float* bv    = (const float*)d_in[8];
  const float* wp    = (const float*)d_in[9];
  const float* bp    = (const float*)d_in[10];
  float* out = (float*)d_out;

  char* ws = (char*)d_ws;
  const size_t MC = (size_t)M_ROWS * C_DIM;
  float* partials      = (float*)ws;                          // 512 x 2 floats (4 KB)
  unsigned short* wT   = (unsigned short*)(ws + 4096);        // 4 x 256x256 bf16
  unsigned short* qb   = wT + 4 * 65536;
  unsigned short* kbuf = qb + MC;
  unsigned short* vb   = kbuf + MC;                           // plane-1 alias
  unsigned short* vTb  = vb + MC;
  unsigned short* pl0  = vTb + MC;                            // O partial planes 0,2,3
  unsigned short* pl2  = pl0 + MC;
  unsigned short* pl3  = pl2 + MC;
  float* lbuf          = (float*)(pl3 + MC);                  // 4 x 16384 floats
  unsigned short* pl1  = vb;

  prep<<<768, 256, 0, stream>>>(x, wq, wk, wv, wp, partials, wT);
  qkv_gemm<<<dim3(256, 2), 256, 0, stream>>>(x, wT, partials, gamma, beta,
                                             bq, bk, bv, qb, kbuf, vTb);
  attn_part<<<512, 256, 0, stream>>>(qb, kbuf, vTb, pl0, pl1, pl2, pl3, lbuf);
  proj_gemm<<<dim3(256, 2), 256, 0, stream>>>(pl0, pl1, pl2, pl3, lbuf,
                                              wT + 3 * 65536, bp, x, out);
}